// Round 6
// baseline (209.308 us; speedup 1.0000x reference)
//
#include <hip/hip_runtime.h>

#define BB 2
#define SS 4096
#define DD 768
#define HH 12
#define HDD 64
#define W1C 256
#define NCC 16
#define GG 8

typedef unsigned short u16;
typedef __attribute__((ext_vector_type(4))) unsigned short u16x4;
typedef __attribute__((ext_vector_type(8))) unsigned short u16x8;
typedef __attribute__((ext_vector_type(8))) short s16x8;
typedef __attribute__((ext_vector_type(4))) float f32x4;

__device__ __forceinline__ float b2f(u16 u) {
  union { unsigned int i; float f; } v;
  v.i = ((unsigned int)u) << 16;
  return v.f;
}
__device__ __forceinline__ u16 f2b(float f) {
  union { float f; unsigned int i; } v;
  v.f = f;
  unsigned int r = v.i + 0x7FFFu + ((v.i >> 16) & 1u);
  return (u16)(r >> 16);
}
__device__ __forceinline__ float fexp2(float x) {
#if __has_builtin(__builtin_amdgcn_exp2f)
  return __builtin_amdgcn_exp2f(x);
#else
  return exp2f(x);
#endif
}
__device__ __forceinline__ unsigned pk_bf16(float lo, float hi) {
  unsigned r;
  asm("v_cvt_pk_bf16_f32 %0, %1, %2" : "=v"(r) : "v"(lo), "v"(hi));
  return r;
}
__device__ __forceinline__ void load_lds16(const void* g, void* l) {
  __builtin_amdgcn_global_load_lds(
      (const __attribute__((address_space(1))) unsigned int*)g,
      (__attribute__((address_space(3))) unsigned int*)l, 16, 0, 0);
}

#define QSCALE 0.18033688011112042f  // 0.125 * log2(e)

// ---------------------------------------------------------------------------
// fp32 -> bf16 bulk convert (8 elems/thread)
// ---------------------------------------------------------------------------
__global__ __launch_bounds__(256) void cvt_f32_bf16(
    const float* __restrict__ in, u16* __restrict__ out, int n8) {
  int i = blockIdx.x * 256 + threadIdx.x;
  if (i >= n8) return;
  const float4* p = (const float4*)(in + (size_t)i * 8);
  float4 a = p[0], b = p[1];
  u16x8 o;
  o[0] = f2b(a.x); o[1] = f2b(a.y); o[2] = f2b(a.z); o[3] = f2b(a.w);
  o[4] = f2b(b.x); o[5] = f2b(b.y); o[6] = f2b(b.z); o[7] = f2b(b.w);
  *(u16x8*)(out + (size_t)i * 8) = o;
}

// ---------------------------------------------------------------------------
// Transpose + convert 6 weight matrices [768][768] fp32 (W[k][n]) into
// WT[mat][n][k] bf16. 64x64 LDS tiles.
// ---------------------------------------------------------------------------
struct WtArgs { const float* W[6]; };

__global__ __launch_bounds__(256) void transpose_wt(WtArgs wa,
                                                    u16* __restrict__ WT) {
  __shared__ float T[64][65];
  const int mat = blockIdx.z;
  const int k0 = blockIdx.y * 64;
  const int n0 = blockIdx.x * 64;
  const float* __restrict__ W = wa.W[mat];
  const int t = threadIdx.x;
#pragma unroll
  for (int i = 0; i < 4; i++) {
    int idx4 = t + i * 256;
    int r = idx4 >> 4, c4 = idx4 & 15;
    float4 v = *(const float4*)(W + (size_t)(k0 + r) * 768 + n0 + c4 * 4);
    T[r][c4 * 4 + 0] = v.x; T[r][c4 * 4 + 1] = v.y;
    T[r][c4 * 4 + 2] = v.z; T[r][c4 * 4 + 3] = v.w;
  }
  __syncthreads();
#pragma unroll
  for (int i = 0; i < 2; i++) {
    int ci = t + i * 256;
    int nl = ci >> 3, k8 = ci & 7;
    u16x8 o;
#pragma unroll
    for (int jj = 0; jj < 8; jj++) o[jj] = f2b(T[k8 * 8 + jj][nl]);
    *(u16x8*)(WT + ((size_t)mat * 768 + n0 + nl) * 768 + k0 + k8 * 8) = o;
  }
}

// ---------------------------------------------------------------------------
// Deep-pipelined bf16 MFMA GEMM (T3+T4+T5). 512 threads = 8 waves (2M x 4N).
// MODE 0: 256x256 tile, 5 concat matrices (grid 480), bf16 out scattered,
//         matrix 0 = Q scaled 0.125*log2e.
// MODE 1: 128x256 tile, Wo (grid 192), fp32 out row-major.
// BK=64; 2-deep K-tile prefetch with counted vmcnt (never 0 in main loop);
// raw s_barrier (no syncthreads drain); (row&7)-XOR 16B-slot LDS swizzle on
// both sides; setprio around MFMA clusters; bijective XCD grid swizzle.
// ---------------------------------------------------------------------------
struct BiasArgs { const float* bias[5]; };

template <int MODE>
__global__ __launch_bounds__(512, 1) void gemm_bf16(
    const u16* __restrict__ A, const u16* __restrict__ WT, BiasArgs ba,
    u16* __restrict__ outb, float* __restrict__ outf) {
  constexpr int BM = (MODE == 0) ? 256 : 128;
  constexpr int WM = BM / 2;           // per-wave M rows
  constexpr int MHAL = BM / 128;       // m-half count (2 or 1)
  constexpr int ATILE = BM * 64 * 2;   // bytes
  constexpr int BTILE = 256 * 64 * 2;
  constexpr int BUFB = ATILE + BTILE;
  constexpr int ACH = ATILE / 1024;    // 1KB chunks (32 or 16)
  constexpr int ALD = ACH / 8;         // A loads per thread per tile (4 or 2)
  constexpr int NTL = (MODE == 0) ? 15 : 3;   // n-tiles of 256
  constexpr int NWG = (MODE == 0) ? 480 : 192;
  constexpr int NT = 12;               // K tiles (768/64)

  extern __shared__ __align__(16) char smem[];

  const int tid = threadIdx.x;
  const int w = tid >> 6, l = tid & 63;
  const int lq = l & 15, g = l >> 4;
  const int wm = w >> 2, wn = w & 3;

  // bijective XCD swizzle
  const int cpx = NWG >> 3;
  const int id = (int)blockIdx.x;
  const int swz = (id & 7) * cpx + (id >> 3);
  const int bm = swz / NTL, bn = swz % NTL;
  const int m0 = bm * BM;
  const int nw0 = bn * 256;  // flat WT row base
  const int wsel = (MODE == 0) ? (bn / 3) : 0;
  const int nmat0 = (MODE == 0) ? ((bn % 3) * 256) : (bn * 256);
  const float* __restrict__ bias = ba.bias[wsel];

  f32x4 acc[MHAL * 4][4];
#pragma unroll
  for (int i = 0; i < MHAL * 4; i++)
#pragma unroll
    for (int j = 0; j < 4; j++) acc[i][j] = (f32x4){0.f, 0.f, 0.f, 0.f};

  // ---- staging helper: tile t -> buf[t&1] (linear LDS dest, inverse-
  // swizzled global source; LDS slot sl holds global slot sl^(row&7)) ----
  auto stage = [&](int t) {
    const int k0 = t * 64;
    char* uA = smem + (t & 1) * BUFB;
    char* uB = uA + ATILE;
#pragma unroll
    for (int j = 0; j < ALD; j++) {
      const int ci = j * 8 + w;
      const int p = ci * 64 + l;
      const int row = p >> 3, sl = p & 7;
      load_lds16(A + (size_t)(m0 + row) * 768 + k0 + ((sl ^ (row & 7)) * 8),
                 uA + ci * 1024);
    }
#pragma unroll
    for (int j = 0; j < 4; j++) {
      const int ci = j * 8 + w;
      const int p = ci * 64 + l;
      const int row = p >> 3, sl = p & 7;
      load_lds16(WT + (size_t)(nw0 + row) * 768 + k0 + ((sl ^ (row & 7)) * 8),
                 uB + ci * 1024);
    }
  };

  // ---- prologue: stage tiles 0,1; wait tile0 ----
  stage(0);
  stage(1);
  if constexpr (MODE == 0)
    asm volatile("s_waitcnt vmcnt(8)" ::: "memory");
  else
    asm volatile("s_waitcnt vmcnt(6)" ::: "memory");
  __builtin_amdgcn_sched_barrier(0);
  __builtin_amdgcn_s_barrier();
  __builtin_amdgcn_sched_barrier(0);

  // ---- main loop ----
  for (int kt = 0; kt < NT; kt++) {
    const int cur = kt & 1;
    const u16* rA = (const u16*)(smem + cur * BUFB);
    const u16* rB = (const u16*)(smem + cur * BUFB + ATILE);

#pragma unroll
    for (int nh = 0; nh < 2; nh++) {
      s16x8 bf[2][2];
#pragma unroll
      for (int nj = 0; nj < 2; nj++) {
        const int r = wn * 64 + (nh * 2 + nj) * 16 + lq;
#pragma unroll
        for (int ks = 0; ks < 2; ks++)
          bf[nj][ks] =
              *(const s16x8*)(rB + r * 64 + (((ks * 4 + g) ^ (r & 7)) * 8));
      }
#pragma unroll
      for (int mh = 0; mh < MHAL; mh++) {
        s16x8 af[4][2];
#pragma unroll
        for (int mi = 0; mi < 4; mi++) {
          const int r = wm * WM + (mh * 4 + mi) * 16 + lq;
#pragma unroll
          for (int ks = 0; ks < 2; ks++)
            af[mi][ks] =
                *(const s16x8*)(rA + r * 64 + (((ks * 4 + g) ^ (r & 7)) * 8));
        }
        __builtin_amdgcn_s_setprio(1);
#pragma unroll
        for (int mi = 0; mi < 4; mi++)
#pragma unroll
          for (int nj = 0; nj < 2; nj++)
#pragma unroll
            for (int ks = 0; ks < 2; ks++)
              acc[mh * 4 + mi][nh * 2 + nj] =
                  __builtin_amdgcn_mfma_f32_16x16x32_bf16(
                      af[mi][ks], bf[nj][ks], acc[mh * 4 + mi][nh * 2 + nj],
                      0, 0, 0);
        __builtin_amdgcn_s_setprio(0);
      }
    }

    // all our ds_reads of buf[cur] complete -> safe to restage it
    asm volatile("s_waitcnt lgkmcnt(0)" ::: "memory");
    __builtin_amdgcn_sched_barrier(0);
    __builtin_amdgcn_s_barrier();
    __builtin_amdgcn_sched_barrier(0);
    if (kt < NT - 2) stage(kt + 2);
    // tile kt+1 landed (kt+2's loads stay in flight)
    if (kt < NT - 2) {
      if constexpr (MODE == 0)
        asm volatile("s_waitcnt vmcnt(8)" ::: "memory");
      else
        asm volatile("s_waitcnt vmcnt(6)" ::: "memory");
    } else {
      asm volatile("s_waitcnt vmcnt(0)" ::: "memory");
    }
    __builtin_amdgcn_sched_barrier(0);
    __builtin_amdgcn_s_barrier();
    __builtin_amdgcn_sched_barrier(0);
  }

  // ---- epilogue ----
  if (MODE == 0) {
    const float scale = (wsel == 0) ? QSCALE : 1.0f;
    u16* outw = outb + (size_t)wsel * ((size_t)BB * HH * SS * HDD);
#pragma unroll
    for (int nj = 0; nj < 4; nj++) {
      const int c = nmat0 + wn * 64 + nj * 16 + lq;
      const float bv = bias[c];
      const int h = c >> 6, hd = c & 63;
#pragma unroll
      for (int mi = 0; mi < MHAL * 4; mi++) {
#pragma unroll
        for (int r = 0; r < 4; r++) {
          const int m = m0 + wm * WM + mi * 16 + g * 4 + r;
          const int b = m >> 12, s = m & 4095;
          outw[((size_t)(b * HH + h) * SS + s) * HDD + hd] =
              f2b((acc[mi][nj][r] + bv) * scale);
        }
      }
    }
  } else {
#pragma unroll
    for (int nj = 0; nj < 4; nj++) {
      const int c = nmat0 + wn * 64 + nj * 16 + lq;
      const float bv = bias[c];
#pragma unroll
      for (int mi = 0; mi < MHAL * 4; mi++) {
#pragma unroll
        for (int r = 0; r < 4; r++) {
          const int m = m0 + wm * WM + mi * 16 + g * 4 + r;
          outf[(size_t)m * 768 + c] = acc[mi][nj][r] + bv;
        }
      }
    }
  }
}

// ---------------------------------------------------------------------------
// qg projection: QG[bh][qi][d] = (hs[b,qi,:] @ Wqg + bqg)[h*64+d] * QSCALE
// for qi<8; rows 8..15 zeroed. bf16 out. Grid = 24 (bh).
// ---------------------------------------------------------------------------
__global__ __launch_bounds__(256) void qg_proj(
    const float* __restrict__ hs, const float* __restrict__ Wqg,
    const float* __restrict__ bqg, u16* __restrict__ QG) {
  __shared__ float hsL[8][768];
  const int bh = blockIdx.x;
  const int b = bh / HH, h = bh % HH;
  const int t = threadIdx.x;
#pragma unroll
  for (int i = 0; i < 6; i++) {
    int idx = t + i * 256;  // 1536 float4 = 8 rows x 192
    int row = idx / 192, c4 = idx % 192;
    *(float4*)&hsL[row][c4 * 4] =
        *(const float4*)(hs + ((size_t)b * SS + row) * DD + c4 * 4);
  }
  __syncthreads();
#pragma unroll
  for (int rep = 0; rep < 2; rep++) {
    int qi = rep * 4 + (t >> 6);
    int d = t & 63, n = h * 64 + d;
    float acc = bqg[n];
    for (int k = 0; k < DD; k++)
      acc = fmaf(hsL[qi][k], Wqg[(size_t)k * DD + n], acc);
    QG[((size_t)bh * 16 + qi) * 64 + d] = f2b(acc * QSCALE);
  }
#pragma unroll
  for (int i = 0; i < 2; i++) {
    int idx = t + i * 256;
    int row = 8 + (idx >> 6), d = idx & 63;
    QG[((size_t)bh * 16 + row) * 64 + d] = 0;
  }
}

// ---------------------------------------------------------------------------
// MFMA attention. GLOBAL=0: banded sliding-window + global-key mini-tile,
// one WG = 64 queries of one (b,h); 10 key tiles of 64; writes normalized
// bf16 ATT [B,S,D]. GLOBAL=1: global tokens (16 padded queries) vs 512-key
// split; per-wave tiles; writes fp32 partials (num, den).
// ---------------------------------------------------------------------------
template <int GLOBAL>
__global__ __launch_bounds__(256) void attn_mfma(
    const u16* __restrict__ Q, const u16* __restrict__ K,
    const u16* __restrict__ V, const int* __restrict__ amask,
    u16* __restrict__ ATT, float* __restrict__ Pnum,
    float* __restrict__ Pden) {
  extern __shared__ __align__(16) char smem[];
  const int tid = threadIdx.x;
  const int w = tid >> 6, lane = tid & 63;
  const int lq = lane & 15, g = lane >> 4;
  const int h = blockIdx.y, b = blockIdx.z;
  const int bh = b * HH + h;
  const size_t bhs = (size_t)bh * SS;
  const int q0 = GLOBAL ? 0 : (int)blockIdx.x * 64;
  const int split = GLOBAL ? (int)blockIdx.x : 0;

  char* Kl;
  char* VT;
  if constexpr (GLOBAL) {
    Kl = smem + w * 16384;
    VT = Kl + 8192;
  } else {
    Kl = smem;
    VT = smem + 8192;
  }

  s16x8 qf[2];
  {
    const u16* qp = GLOBAL ? (Q + ((size_t)bh * 16 + lq) * 64)
                           : (Q + (bhs + q0 + w * 16 + lq) * 64);
    qf[0] = *(const s16x8*)(qp + g * 8);
    qf[1] = *(const s16x8*)(qp + 32 + g * 8);
  }

  f32x4 oacc[4];
#pragma unroll
  for (int i = 0; i < 4; i++) oacc[i] = (f32x4){0.f, 0.f, 0.f, 0.f};
  float denom = 0.f;

  const int NT = GLOBAL ? 2 : 10;
  for (int kt = 0; kt < NT; kt++) {
    int j0, klimit;
    bool bandfree;
    if constexpr (GLOBAL) {
      j0 = split * 512 + (w * 2 + kt) * 64;
      bandfree = true;
      klimit = 64;
    } else {
      if (kt < 9) { j0 = q0 - 256 + kt * 64; bandfree = false; klimit = 64; }
      else        { j0 = 0;                  bandfree = true;  klimit = 8; }
    }

    int jm = j0 + lane;
    int mv = ((unsigned)jm < (unsigned)SS) ? amask[b * SS + jm] : -1;
    bool okk = (mv >= 0) && (lane < klimit);
    unsigned long long vm = __ballot(okk);

    // ---- staging ----
    if constexpr (GLOBAL) {
      asm volatile("s_waitcnt lgkmcnt(0)" ::: "memory");
      const u16* Ks = K + bhs * 64 + (size_t)j0 * 64;
#pragma unroll
      for (int i = 0; i < 8; i++) {
        int ci = i * 64 + lane;
        int row = ci >> 3, cc = ci & 7, cs = cc ^ (row & 7);
        load_lds16(Ks + row * 64 + cs * 8, Kl + i * 1024);
      }
      const u16* Vs = V + bhs * 64 + (size_t)j0 * 64;
#pragma unroll
      for (int p = 0; p < 8; p++) {
        u16x8 vv = *(const u16x8*)(Vs + (size_t)lane * 64 + p * 8);
#pragma unroll
        for (int e = 0; e < 8; e++)
          *(u16*)(VT + (p * 8 + e) * 128 + ((lane * 2) ^ (e << 4))) = vv[e];
      }
      asm volatile("s_waitcnt vmcnt(0) lgkmcnt(0)" ::: "memory");
    } else {
      __syncthreads();
      if (j0 >= 0 && j0 + 64 <= SS) {
        const u16* Ks = K + bhs * 64 + (size_t)j0 * 64;
#pragma unroll
        for (int i = 0; i < 2; i++) {
          int ci = (i * 4 + w) * 64 + lane;
          int row = ci >> 3, cc = ci & 7, cs = cc ^ (row & 7);
          load_lds16(Ks + row * 64 + cs * 8, Kl + (i * 4 + w) * 1024);
        }
      } else {
#pragma unroll
        for (int i = 0; i < 2; i++) {
          int ci = (i * 4 + w) * 64 + lane;
          int row = ci >> 3, cc = ci & 7, cs = cc ^ (row & 7);
          int jj = j0 + row;
          u16x8 val;
#pragma unroll
          for (int e = 0; e < 8; e++) val[e] = 0;
          if ((unsigned)jj < (unsigned)SS)
            val = *(const u16x8*)(K + (bhs + jj) * 64 + cs * 8);
          *(u16x8*)(Kl + ci * 16) = val;
        }
      }
#pragma unroll
      for (int p = 0; p < 2; p++) {
        int d0 = p * 32 + w * 8;
        int jj = j0 + lane;
        u16x8 vv;
#pragma unroll
        for (int e = 0; e < 8; e++) vv[e] = 0;
        if ((unsigned)jj < (unsigned)SS)
          vv = *(const u16x8*)(V + (bhs + jj) * 64 + d0);
#pragma unroll
        for (int e = 0; e < 8; e++)
          *(u16*)(VT + (d0 + e) * 128 + ((lane * 2) ^ (e << 4))) = vv[e];
      }
      asm volatile("s_waitcnt vmcnt(0)" ::: "memory");
      __syncthreads();
    }

    // ---- QK^T ----
    f32x4 sc[4];
#pragma unroll
    for (int i = 0; i < 4; i++) sc[i] = (f32x4){0.f, 0.f, 0.f, 0.f};
#pragma unroll
    for (int s = 0; s < 2; s++) {
#pragma unroll
      for (int ks = 0; ks < 4; ks++) {
        s16x8 kf = *(const s16x8*)(Kl + (ks * 16 + lq) * 128 +
                                   (((s * 4 + g) ^ (lq & 7)) << 4));
        sc[ks] = __builtin_amdgcn_mfma_f32_16x16x32_bf16(kf, qf[s], sc[ks],
                                                          0, 0, 0);
      }
    }

    // ---- mask + exp2 -> P ----
    {
      const unsigned mlo = (unsigned)vm, mhi = (unsigned)(vm >> 32);
      const int q_abs = q0 + w * 16 + lq;
      bool allin = bandfree;
      if constexpr (!GLOBAL) {
        const int qw = q0 + w * 16;
        allin = bandfree || (j0 >= qw - 241 && j0 <= qw + 193);
      }
      const bool fast = (vm == ~0ull) && allin;
      const int ddq = j0 + g * 4 - q_abs;
      const int gsh = g * 4;
      if (fast) {
#pragma unroll
        for (int ks = 0; ks < 4; ks++)
#pragma unroll
          for (int r = 0; r < 4; r++) {
            float p = fexp2(sc[ks][r]);
            sc[ks][r] = p;
            denom += p;
          }
      } else {
#pragma unroll
        for (int ks = 0; ks < 4; ks++)
#pragma unroll
          for (int r = 0; r < 4; r++) {
            float e = fexp2(sc[ks][r]);
            unsigned bit =
                ((ks < 2 ? mlo : mhi) >> (gsh + ((ks & 1) * 16 + r))) & 1u;
            bool ok = bit && (allin ||
                              (unsigned)(ddq + ks * 16 + r + 256) <= 512u);
            float p = ok ? e : 0.f;
            sc[ks][r] = p;
            denom += p;
          }
      }
    }

    // ---- P^T fragments + PV ----
#pragma unroll
    for (int s = 0; s < 2; s++) {
      const int srcA = lq + ((g & 1) << 5);
      const bool hiSel = g >= 2;
      float L[4], H[4];
#pragma unroll
      for (int r = 0; r < 4; r++) {
        float a0 = __shfl(sc[2 * s][r], srcA);
        float a1 = __shfl(sc[2 * s + 1][r], srcA);
        L[r] = hiSel ? a1 : a0;
        float b0 = __shfl(sc[2 * s][r], srcA + 16);
        float b1 = __shfl(sc[2 * s + 1][r], srcA + 16);
        H[r] = hiSel ? b1 : b0;
      }
      union { unsigned u[4]; s16x8 v; } pf;
      pf.u[0] = pk_bf16(L[0], L[1]);
      pf.u[1] = pk_bf16(L[2], L[3]);
      pf.u[2] = pk_bf16(H[0], H[1]);
      pf.u[3] = pk_bf16(H[2], H[3]);
#pragma unroll
      for (int dblk = 0; dblk < 4; dblk++) {
        s16x8 vf = *(const s16x8*)(VT + (dblk * 16 + lq) * 128 +
                                   (((s * 4 + g) ^ (lq & 7)) << 4));
        oacc[dblk] = __builtin_amdgcn_mfma_f32_16x16x32_bf16(vf, pf.v,
                                                              oacc[dblk],
                                                              0, 0, 0);
      }
    }
  }

  // ---- epilogue ----
  denom += __shfl_xor(denom, 16);
  denom += __shfl_xor(denom, 32);
  if constexpr (!GLOBAL) {
    const int q_abs = q0 + w * 16 + lq;
    const float rowscale = (amask[b * SS + q_abs] >= 0) ? (1.f / denom) : 0.f;
    u16* orow = ATT + ((size_t)b * SS + q_abs) * DD + h * 64;
#pragma unroll
    for (int dblk = 0; dblk < 4; dblk++) {
      u16x4 o;
#pragma unroll
      for (int r = 0; r < 4; r++) o[r] = f2b(oacc[dblk][r] * rowscale);
      *(u16x4*)(orow + dblk * 16 + g * 4) = o;
    }
  } else {
    const int pidx = split * 4 + w;
    float* np = Pnum + ((size_t)bh * 32 + pidx) * 1024;
#pragma unroll
    for (int dblk = 0; dblk < 4; dblk++)
#pragma unroll
      for (int r = 0; r < 4; r++)
        np[(dblk * 16 + g * 4 + r) * 16 + lq] = oacc[dblk][r];
    Pden[((size_t)bh * 32 + pidx) * 16 + lq] = denom;
  }
}

// ---------------------------------------------------------------------------
// Merge global-token partials and overwrite ATT rows < G.
// ---------------------------------------------------------------------------
__global__ __launch_bounds__(512) void gmerge(const float* __restrict__ Pnum,
                                              const float* __restrict__ Pden,
                                              u16* __restrict__ ATT) {
  const int bh = blockIdx.x;
  const int b = bh / HH, h = bh % HH;
  const int t = threadIdx.x;
  const int q = t >> 6, d = t & 63;
  float num = 0.f, den = 0.f;
#pragma unroll 4
  for (int p = 0; p < 32; p++) {
    num += Pnum[((size_t)bh * 32 + p) * 1024 + d * 16 + q];
    den += Pden[((size_t)bh * 32 + p) * 16 + q];
  }
  ATT[((size_t)b * SS + q) * DD + h * 64 + d] = f2b(num / den);
}

// ---------------------------------------------------------------------------
extern "C" void kernel_launch(void* const* d_in, const int* in_sizes, int n_in,
                              void* d_out, int out_size, void* d_ws,
                              size_t ws_size, hipStream_t stream) {
  const float* hs = (const float*)d_in[0];
  const int* amask = (const int*)d_in[1];
  const float* Wq = (const float*)d_in[2];
  const float* bq = (const float*)d_in[3];
  const float* Wk = (const float*)d_in[4];
  const float* bk = (const float*)d_in[5];
  const float* Wv = (const float*)d_in[6];
  const float* bv = (const float*)d_in[7];
  const float* Wqg = (const float*)d_in[8];
  const float* bqg = (const float*)d_in[9];
  const float* Wkg = (const float*)d_in[10];
  const float* bkg = (const float*)d_in[11];
  const float* Wvg = (const float*)d_in[12];
  const float* bvg = (const float*)d_in[13];
  const float* Wo = (const float*)d_in[14];
  const float* bo = (const float*)d_in[15];
  float* out = (float*)d_out;

  char* ws = (char*)d_ws;
  const size_t QSZB = (size_t)BB * HH * SS * HDD * 2;  // 12582912 B
  u16* Qb = (u16*)(ws + 0);
  u16* Kb = (u16*)(ws + QSZB);
  u16* Vb = (u16*)(ws + 2 * QSZB);
  u16* KGb = (u16*)(ws + 3 * QSZB);
  u16* VGb = (u16*)(ws + 4 * QSZB);
  u16* Ab = (u16*)(ws + 5 * QSZB);
  u16* WTb = (u16*)(ws + 6 * QSZB);                     // 7077888 B
  u16* ATTb = (u16*)(ws + 6 * QSZB + 7077888);          // QSZB
  u16* QGb = (u16*)(ws + 7 * QSZB + 7077888);           // 49152 B
  float* Pnum = (float*)(ws + 7 * QSZB + 7077888 + 49152);   // 3145728 B
  float* Pden = (float*)(ws + 7 * QSZB + 7077888 + 49152 + 3145728);  // 49152

  // 1) convert hs -> bf16 A
  hipLaunchKernelGGL(cvt_f32_bf16, dim3(3072), dim3(256), 0, stream, hs, Ab,
                     (int)((size_t)BB * SS * DD / 8));

  // 2) transpose+convert 6 weight matrices -> WT[mat][n][k] bf16
  WtArgs wa;
  wa.W[0] = Wq; wa.W[1] = Wk; wa.W[2] = Wv;
  wa.W[3] = Wkg; wa.W[4] = Wvg; wa.W[5] = Wo;
  hipLaunchKernelGGL(transpose_wt, dim3(12, 12, 6), dim3(256), 0, stream, wa,
                     WTb);

  // 3) fused projections (bf16 MFMA, deep pipeline): Q,K,V,KG,VG
  BiasArgs b0;
  b0.bias[0] = bq; b0.bias[1] = bk; b0.bias[2] = bv;
  b0.bias[3] = bkg; b0.bias[4] = bvg;
  hipLaunchKernelGGL((gemm_bf16<0>), dim3(480), dim3(512), 131072, stream,
                     Ab, WTb, b0, Qb, (float*)nullptr);

  // 4) qg projection -> QGb
  hipLaunchKernelGGL(qg_proj, dim3(24), dim3(256), 0, stream, hs, Wqg, bqg,
                     QGb);

  // 5) global-token attention partials (reads KGb/VGb/QGb)
  hipLaunchKernelGGL((attn_mfma<1>), dim3(8, HH, BB), dim3(256), 65536,
                     stream, QGb, KGb, VGb, amask, (u16*)nullptr, Pnum, Pden);

  // 6) banded attention -> ATT (bf16)
  hipLaunchKernelGGL((attn_mfma<0>), dim3(64, HH, BB), dim3(256), 16384,
                     stream, Qb, Kb, Vb, amask, ATTb, (float*)nullptr,
                     (float*)nullptr);

  // 7) merge global-token rows into ATT
  hipLaunchKernelGGL(gmerge, dim3(24), dim3(512), 0, stream, Pnum, Pden, ATTb);

  // 8) output projection (bf16 MFMA, fp32 out)
  BiasArgs b1;
  for (int i = 0; i < 5; i++) b1.bias[i] = bo;
  hipLaunchKernelGGL((gemm_bf16<1>), dim3(192), dim3(512), 98304, stream,
                     ATTb, WTb + (size_t)5 * 768 * 768, b1, (u16*)nullptr,
                     out);
}

// Round 7
// 203.111 us; speedup vs baseline: 1.0305x; 1.0305x over previous
//
#include <hip/hip_runtime.h>

#define BB 2
#define SS 4096
#define DD 768
#define HH 12
#define HDD 64
#define W1C 256
#define NCC 16
#define GG 8

typedef unsigned short u16;
typedef __attribute__((ext_vector_type(4))) unsigned short u16x4;
typedef __attribute__((ext_vector_type(8))) unsigned short u16x8;
typedef __attribute__((ext_vector_type(8))) short s16x8;
typedef __attribute__((ext_vector_type(4))) float f32x4;

__device__ __forceinline__ float b2f(u16 u) {
  union { unsigned int i; float f; } v;
  v.i = ((unsigned int)u) << 16;
  return v.f;
}
__device__ __forceinline__ u16 f2b(float f) {
  union { float f; unsigned int i; } v;
  v.f = f;
  unsigned int r = v.i + 0x7FFFu + ((v.i >> 16) & 1u);
  return (u16)(r >> 16);
}
__device__ __forceinline__ float fexp2(float x) {
#if __has_builtin(__builtin_amdgcn_exp2f)
  return __builtin_amdgcn_exp2f(x);
#else
  return exp2f(x);
#endif
}
__device__ __forceinline__ unsigned pk_bf16(float lo, float hi) {
  unsigned r;
  asm("v_cvt_pk_bf16_f32 %0, %1, %2" : "=v"(r) : "v"(lo), "v"(hi));
  return r;
}
__device__ __forceinline__ void load_lds16(const void* g, void* l) {
  __builtin_amdgcn_global_load_lds(
      (const __attribute__((address_space(1))) unsigned int*)g,
      (__attribute__((address_space(3))) unsigned int*)l, 16, 0, 0);
}

#define QSCALE 0.18033688011112042f  // 0.125 * log2(e)

// ---------------------------------------------------------------------------
// fp32 -> bf16 bulk convert (8 elems/thread)
// ---------------------------------------------------------------------------
__global__ __launch_bounds__(256) void cvt_f32_bf16(
    const float* __restrict__ in, u16* __restrict__ out, int n8) {
  int i = blockIdx.x * 256 + threadIdx.x;
  if (i >= n8) return;
  const float4* p = (const float4*)(in + (size_t)i * 8);
  float4 a = p[0], b = p[1];
  u16x8 o;
  o[0] = f2b(a.x); o[1] = f2b(a.y); o[2] = f2b(a.z); o[3] = f2b(a.w);
  o[4] = f2b(b.x); o[5] = f2b(b.y); o[6] = f2b(b.z); o[7] = f2b(b.w);
  *(u16x8*)(out + (size_t)i * 8) = o;
}

// ---------------------------------------------------------------------------
// Transpose + convert 6 weight matrices [768][768] fp32 (W[k][n]) into
// WT[mat][n][k] bf16. 64x64 LDS tiles.
// ---------------------------------------------------------------------------
struct WtArgs { const float* W[6]; };

__global__ __launch_bounds__(256) void transpose_wt(WtArgs wa,
                                                    u16* __restrict__ WT) {
  __shared__ float T[64][65];
  const int mat = blockIdx.z;
  const int k0 = blockIdx.y * 64;
  const int n0 = blockIdx.x * 64;
  const float* __restrict__ W = wa.W[mat];
  const int t = threadIdx.x;
#pragma unroll
  for (int i = 0; i < 4; i++) {
    int idx4 = t + i * 256;
    int r = idx4 >> 4, c4 = idx4 & 15;
    float4 v = *(const float4*)(W + (size_t)(k0 + r) * 768 + n0 + c4 * 4);
    T[r][c4 * 4 + 0] = v.x; T[r][c4 * 4 + 1] = v.y;
    T[r][c4 * 4 + 2] = v.z; T[r][c4 * 4 + 3] = v.w;
  }
  __syncthreads();
#pragma unroll
  for (int i = 0; i < 2; i++) {
    int ci = t + i * 256;
    int nl = ci >> 3, k8 = ci & 7;
    u16x8 o;
#pragma unroll
    for (int jj = 0; jj < 8; jj++) o[jj] = f2b(T[k8 * 8 + jj][nl]);
    *(u16x8*)(WT + ((size_t)mat * 768 + n0 + nl) * 768 + k0 + k8 * 8) = o;
  }
}

// ---------------------------------------------------------------------------
// bf16 MFMA GEMM, 3-buffer LDS ring. 512 threads = 8 waves (2M x 4N),
// tile 128x256, BK=64. stage(t+2) issued at TOP of tile t (overlaps MFMA),
// single s_barrier + counted vmcnt(6) per K-step (never a full drain in the
// main loop). (row&7)-XOR 16B-slot LDS swizzle both sides; bijective XCD
// grid swizzle.
// MODE 0: 5 concat matrices (grid 960), bf16 out scattered to [B,H,S,HD],
//         matrix 0 = Q scaled 0.125*log2e.
// MODE 1: Wo (grid 192), fp32 out row-major.
// ---------------------------------------------------------------------------
struct BiasArgs { const float* bias[5]; };

template <int MODE>
__global__ __launch_bounds__(512, 1) void gemm_bf16(
    const u16* __restrict__ A, const u16* __restrict__ WT, BiasArgs ba,
    u16* __restrict__ outb, float* __restrict__ outf) {
  constexpr int NTL = (MODE == 0) ? 15 : 3;   // n-tiles of 256
  constexpr int NWG = 64 * NTL;
  constexpr int NT = 12;                      // K tiles (768/64)
  constexpr int ABYTES = 128 * 64 * 2;        // 16384
  constexpr int BBYTES = 256 * 64 * 2;        // 32768
  constexpr int BUFB = ABYTES + BBYTES;       // 49152; x3 = 147456 LDS

  extern __shared__ __align__(16) char smem[];

  const int tid = threadIdx.x;
  const int w = tid >> 6, l = tid & 63;
  const int lq = l & 15, g = l >> 4;
  const int wm = w >> 2, wn = w & 3;

  // bijective XCD swizzle
  const int cpx = NWG >> 3;
  const int id = (int)blockIdx.x;
  const int swz = (id & 7) * cpx + (id >> 3);
  const int bm = swz / NTL, bn = swz % NTL;
  const int m0 = bm * 128;
  const int nw0 = bn * 256;  // flat WT row base
  const int wsel = (MODE == 0) ? (bn / 3) : 0;
  const int nmat0 = (MODE == 0) ? ((bn % 3) * 256) : (bn * 256);
  const float* __restrict__ bias = ba.bias[wsel];

  f32x4 acc[4][4];
#pragma unroll
  for (int i = 0; i < 4; i++)
#pragma unroll
    for (int j = 0; j < 4; j++) acc[i][j] = (f32x4){0.f, 0.f, 0.f, 0.f};

  // stage tile t into buf[t%3]: linear LDS dest, inverse-swizzled global
  // source (LDS slot sl holds global slot sl^(row&7)). 6 loads/thread.
  auto stage = [&](int t) {
    const int k0 = t * 64;
    char* uA = smem + (t % 3) * BUFB;
    char* uB = uA + ABYTES;
#pragma unroll
    for (int j = 0; j < 2; j++) {        // A: 16 chunks of 1KB
      const int ci = j * 8 + w;
      const int p = ci * 64 + l;
      const int row = p >> 3, sl = p & 7;
      load_lds16(A + (size_t)(m0 + row) * 768 + k0 + ((sl ^ (row & 7)) * 8),
                 uA + ci * 1024);
    }
#pragma unroll
    for (int j = 0; j < 4; j++) {        // B: 32 chunks of 1KB
      const int ci = j * 8 + w;
      const int p = ci * 64 + l;
      const int row = p >> 3, sl = p & 7;
      load_lds16(WT + (size_t)(nw0 + row) * 768 + k0 + ((sl ^ (row & 7)) * 8),
                 uB + ci * 1024);
    }
  };

  // ---- prologue: stage 0,1; wait tile0 (6 of 12 outstanding) ----
  stage(0);
  stage(1);
  asm volatile("s_waitcnt vmcnt(6)" ::: "memory");
  __builtin_amdgcn_sched_barrier(0);
  __builtin_amdgcn_s_barrier();
  __builtin_amdgcn_sched_barrier(0);

  // ---- main loop: one barrier + one counted vmcnt per K-step ----
  for (int kt = 0; kt < NT; kt++) {
    const u16* rA = (const u16*)(smem + (kt % 3) * BUFB);
    const u16* rB = (const u16*)(smem + (kt % 3) * BUFB + ABYTES);

    if (kt < NT - 2) stage(kt + 2);   // writes buf[(kt+2)%3]: nobody reads it
    __builtin_amdgcn_sched_barrier(0);

    s16x8 af[4][2], bf[4][2];
#pragma unroll
    for (int mi = 0; mi < 4; mi++) {
      const int r = wm * 64 + mi * 16 + lq;
#pragma unroll
      for (int ks = 0; ks < 2; ks++)
        af[mi][ks] =
            *(const s16x8*)(rA + r * 64 + (((ks * 4 + g) ^ (r & 7)) * 8));
    }
#pragma unroll
    for (int nj = 0; nj < 4; nj++) {
      const int r = wn * 64 + nj * 16 + lq;
#pragma unroll
      for (int ks = 0; ks < 2; ks++)
        bf[nj][ks] =
            *(const s16x8*)(rB + r * 64 + (((ks * 4 + g) ^ (r & 7)) * 8));
    }
#pragma unroll
    for (int mi = 0; mi < 4; mi++)
#pragma unroll
      for (int nj = 0; nj < 4; nj++)
#pragma unroll
        for (int ks = 0; ks < 2; ks++)
          acc[mi][nj] = __builtin_amdgcn_mfma_f32_16x16x32_bf16(
              af[mi][ks], bf[nj][ks], acc[mi][nj], 0, 0, 0);

    // boundary: confirm tile kt+1 landed (tile kt+2's 6 loads may fly on)
    if (kt < NT - 2)
      asm volatile("s_waitcnt vmcnt(6)" ::: "memory");
    else
      asm volatile("s_waitcnt vmcnt(0)" ::: "memory");
    __builtin_amdgcn_sched_barrier(0);
    __builtin_amdgcn_s_barrier();
    __builtin_amdgcn_sched_barrier(0);
  }

  // ---- epilogue ----
  if (MODE == 0) {
    const float scale = (wsel == 0) ? QSCALE : 1.0f;
    u16* outw = outb + (size_t)wsel * ((size_t)BB * HH * SS * HDD);
#pragma unroll
    for (int nj = 0; nj < 4; nj++) {
      const int c = nmat0 + wn * 64 + nj * 16 + lq;
      const float bv = bias[c];
      const int h = c >> 6, hd = c & 63;
#pragma unroll
      for (int mi = 0; mi < 4; mi++) {
#pragma unroll
        for (int r = 0; r < 4; r++) {
          const int m = m0 + wm * 64 + mi * 16 + g * 4 + r;
          const int b = m >> 12, s = m & 4095;
          outw[((size_t)(b * HH + h) * SS + s) * HDD + hd] =
              f2b((acc[mi][nj][r] + bv) * scale);
        }
      }
    }
  } else {
#pragma unroll
    for (int nj = 0; nj < 4; nj++) {
      const int c = nmat0 + wn * 64 + nj * 16 + lq;
      const float bv = bias[c];
#pragma unroll
      for (int mi = 0; mi < 4; mi++) {
#pragma unroll
        for (int r = 0; r < 4; r++) {
          const int m = m0 + wm * 64 + mi * 16 + g * 4 + r;
          outf[(size_t)m * 768 + c] = acc[mi][nj][r] + bv;
        }
      }
    }
  }
}

// ---------------------------------------------------------------------------
// qg projection: QG[bh][qi][d] = (hs[b,qi,:] @ Wqg + bqg)[h*64+d] * QSCALE
// for qi<8; rows 8..15 zeroed. bf16 out. Grid = 24 (bh).
// ---------------------------------------------------------------------------
__global__ __launch_bounds__(256) void qg_proj(
    const float* __restrict__ hs, const float* __restrict__ Wqg,
    const float* __restrict__ bqg, u16* __restrict__ QG) {
  __shared__ float hsL[8][768];
  const int bh = blockIdx.x;
  const int b = bh / HH, h = bh % HH;
  const int t = threadIdx.x;
#pragma unroll
  for (int i = 0; i < 6; i++) {
    int idx = t + i * 256;  // 1536 float4 = 8 rows x 192
    int row = idx / 192, c4 = idx % 192;
    *(float4*)&hsL[row][c4 * 4] =
        *(const float4*)(hs + ((size_t)b * SS + row) * DD + c4 * 4);
  }
  __syncthreads();
#pragma unroll
  for (int rep = 0; rep < 2; rep++) {
    int qi = rep * 4 + (t >> 6);
    int d = t & 63, n = h * 64 + d;
    float acc = bqg[n];
    for (int k = 0; k < DD; k++)
      acc = fmaf(hsL[qi][k], Wqg[(size_t)k * DD + n], acc);
    QG[((size_t)bh * 16 + qi) * 64 + d] = f2b(acc * QSCALE);
  }
#pragma unroll
  for (int i = 0; i < 2; i++) {
    int idx = t + i * 256;
    int row = 8 + (idx >> 6), d = idx & 63;
    QG[((size_t)bh * 16 + row) * 64 + d] = 0;
  }
}

// ---------------------------------------------------------------------------
// MFMA attention. GLOBAL=0: banded sliding-window + global-key mini-tile,
// one WG = 64 queries of one (b,h); 10 key tiles of 64; writes normalized
// bf16 ATT [B,S,D]. GLOBAL=1: global tokens (16 padded queries) vs 512-key
// split; per-wave tiles; writes fp32 partials (num, den).
// ---------------------------------------------------------------------------
template <int GLOBAL>
__global__ __launch_bounds__(256) void attn_mfma(
    const u16* __restrict__ Q, const u16* __restrict__ K,
    const u16* __restrict__ V, const int* __restrict__ amask,
    u16* __restrict__ ATT, float* __restrict__ Pnum,
    float* __restrict__ Pden) {
  extern __shared__ __align__(16) char smem[];
  const int tid = threadIdx.x;
  const int w = tid >> 6, lane = tid & 63;
  const int lq = lane & 15, g = lane >> 4;
  const int h = blockIdx.y, b = blockIdx.z;
  const int bh = b * HH + h;
  const size_t bhs = (size_t)bh * SS;
  const int q0 = GLOBAL ? 0 : (int)blockIdx.x * 64;
  const int split = GLOBAL ? (int)blockIdx.x : 0;

  char* Kl;
  char* VT;
  if constexpr (GLOBAL) {
    Kl = smem + w * 16384;
    VT = Kl + 8192;
  } else {
    Kl = smem;
    VT = smem + 8192;
  }

  s16x8 qf[2];
  {
    const u16* qp = GLOBAL ? (Q + ((size_t)bh * 16 + lq) * 64)
                           : (Q + (bhs + q0 + w * 16 + lq) * 64);
    qf[0] = *(const s16x8*)(qp + g * 8);
    qf[1] = *(const s16x8*)(qp + 32 + g * 8);
  }

  f32x4 oacc[4];
#pragma unroll
  for (int i = 0; i < 4; i++) oacc[i] = (f32x4){0.f, 0.f, 0.f, 0.f};
  float denom = 0.f;

  const int NT = GLOBAL ? 2 : 10;
  for (int kt = 0; kt < NT; kt++) {
    int j0, klimit;
    bool bandfree;
    if constexpr (GLOBAL) {
      j0 = split * 512 + (w * 2 + kt) * 64;
      bandfree = true;
      klimit = 64;
    } else {
      if (kt < 9) { j0 = q0 - 256 + kt * 64; bandfree = false; klimit = 64; }
      else        { j0 = 0;                  bandfree = true;  klimit = 8; }
    }

    int jm = j0 + lane;
    int mv = ((unsigned)jm < (unsigned)SS) ? amask[b * SS + jm] : -1;
    bool okk = (mv >= 0) && (lane < klimit);
    unsigned long long vm = __ballot(okk);

    // ---- staging ----
    if constexpr (GLOBAL) {
      asm volatile("s_waitcnt lgkmcnt(0)" ::: "memory");
      const u16* Ks = K + bhs * 64 + (size_t)j0 * 64;
#pragma unroll
      for (int i = 0; i < 8; i++) {
        int ci = i * 64 + lane;
        int row = ci >> 3, cc = ci & 7, cs = cc ^ (row & 7);
        load_lds16(Ks + row * 64 + cs * 8, Kl + i * 1024);
      }
      const u16* Vs = V + bhs * 64 + (size_t)j0 * 64;
#pragma unroll
      for (int p = 0; p < 8; p++) {
        u16x8 vv = *(const u16x8*)(Vs + (size_t)lane * 64 + p * 8);
#pragma unroll
        for (int e = 0; e < 8; e++)
          *(u16*)(VT + (p * 8 + e) * 128 + ((lane * 2) ^ (e << 4))) = vv[e];
      }
      asm volatile("s_waitcnt vmcnt(0) lgkmcnt(0)" ::: "memory");
    } else {
      __syncthreads();
      if (j0 >= 0 && j0 + 64 <= SS) {
        const u16* Ks = K + bhs * 64 + (size_t)j0 * 64;
#pragma unroll
        for (int i = 0; i < 2; i++) {
          int ci = (i * 4 + w) * 64 + lane;
          int row = ci >> 3, cc = ci & 7, cs = cc ^ (row & 7);
          load_lds16(Ks + row * 64 + cs * 8, Kl + (i * 4 + w) * 1024);
        }
      } else {
#pragma unroll
        for (int i = 0; i < 2; i++) {
          int ci = (i * 4 + w) * 64 + lane;
          int row = ci >> 3, cc = ci & 7, cs = cc ^ (row & 7);
          int jj = j0 + row;
          u16x8 val;
#pragma unroll
          for (int e = 0; e < 8; e++) val[e] = 0;
          if ((unsigned)jj < (unsigned)SS)
            val = *(const u16x8*)(K + (bhs + jj) * 64 + cs * 8);
          *(u16x8*)(Kl + ci * 16) = val;
        }
      }
#pragma unroll
      for (int p = 0; p < 2; p++) {
        int d0 = p * 32 + w * 8;
        int jj = j0 + lane;
        u16x8 vv;
#pragma unroll
        for (int e = 0; e < 8; e++) vv[e] = 0;
        if ((unsigned)jj < (unsigned)SS)
          vv = *(const u16x8*)(V + (bhs + jj) * 64 + d0);
#pragma unroll
        for (int e = 0; e < 8; e++)
          *(u16*)(VT + (d0 + e) * 128 + ((lane * 2) ^ (e << 4))) = vv[e];
      }
      asm volatile("s_waitcnt vmcnt(0)" ::: "memory");
      __syncthreads();
    }

    // ---- QK^T ----
    f32x4 sc[4];
#pragma unroll
    for (int i = 0; i < 4; i++) sc[i] = (f32x4){0.f, 0.f, 0.f, 0.f};
#pragma unroll
    for (int s = 0; s < 2; s++) {
#pragma unroll
      for (int ks = 0; ks < 4; ks++) {
        s16x8 kf = *(const s16x8*)(Kl + (ks * 16 + lq) * 128 +
                                   (((s * 4 + g) ^ (lq & 7)) << 4));
        sc[ks] = __builtin_amdgcn_mfma_f32_16x16x32_bf16(kf, qf[s], sc[ks],
                                                          0, 0, 0);
      }
    }

    // ---- mask + exp2 -> P ----
    {
      const unsigned mlo = (unsigned)vm, mhi = (unsigned)(vm >> 32);
      const int q_abs = q0 + w * 16 + lq;
      bool allin = bandfree;
      if constexpr (!GLOBAL) {
        const int qw = q0 + w * 16;
        allin = bandfree || (j0 >= qw - 241 && j0 <= qw + 193);
      }
      const bool fast = (vm == ~0ull) && allin;
      const int ddq = j0 + g * 4 - q_abs;
      const int gsh = g * 4;
      if (fast) {
#pragma unroll
        for (int ks = 0; ks < 4; ks++)
#pragma unroll
          for (int r = 0; r < 4; r++) {
            float p = fexp2(sc[ks][r]);
            sc[ks][r] = p;
            denom += p;
          }
      } else {
#pragma unroll
        for (int ks = 0; ks < 4; ks++)
#pragma unroll
          for (int r = 0; r < 4; r++) {
            float e = fexp2(sc[ks][r]);
            unsigned bit =
                ((ks < 2 ? mlo : mhi) >> (gsh + ((ks & 1) * 16 + r))) & 1u;
            bool ok = bit && (allin ||
                              (unsigned)(ddq + ks * 16 + r + 256) <= 512u);
            float p = ok ? e : 0.f;
            sc[ks][r] = p;
            denom += p;
          }
      }
    }

    // ---- P^T fragments + PV ----
#pragma unroll
    for (int s = 0; s < 2; s++) {
      const int srcA = lq + ((g & 1) << 5);
      const bool hiSel = g >= 2;
      float L[4], H[4];
#pragma unroll
      for (int r = 0; r < 4; r++) {
        float a0 = __shfl(sc[2 * s][r], srcA);
        float a1 = __shfl(sc[2 * s + 1][r], srcA);
        L[r] = hiSel ? a1 : a0;
        float b0 = __shfl(sc[2 * s][r], srcA + 16);
        float b1 = __shfl(sc[2 * s + 1][r], srcA + 16);
        H[r] = hiSel ? b1 : b0;
      }
      union { unsigned u[4]; s16x8 v; } pf;
      pf.u[0] = pk_bf16(L[0], L[1]);
      pf.u[1] = pk_bf16(L[2], L[3]);
      pf.u[2] = pk_bf16(H[0], H[1]);
      pf.u[3] = pk_bf16(H[2], H[3]);
#pragma unroll
      for (int dblk = 0; dblk < 4; dblk++) {
        s16x8 vf = *(const s16x8*)(VT + (dblk * 16 + lq) * 128 +
                                   (((s * 4 + g) ^ (lq & 7)) << 4));
        oacc[dblk] = __builtin_amdgcn_mfma_f32_16x16x32_bf16(vf, pf.v,
                                                              oacc[dblk],
                                                              0, 0, 0);
      }
    }
  }

  // ---- epilogue ----
  denom += __shfl_xor(denom, 16);
  denom += __shfl_xor(denom, 32);
  if constexpr (!GLOBAL) {
    const int q_abs = q0 + w * 16 + lq;
    const float rowscale = (amask[b * SS + q_abs] >= 0) ? (1.f / denom) : 0.f;
    u16* orow = ATT + ((size_t)b * SS + q_abs) * DD + h * 64;
#pragma unroll
    for (int dblk = 0; dblk < 4; dblk++) {
      u16x4 o;
#pragma unroll
      for (int r = 0; r < 4; r++) o[r] = f2b(oacc[dblk][r] * rowscale);
      *(u16x4*)(orow + dblk * 16 + g * 4) = o;
    }
  } else {
    const int pidx = split * 4 + w;
    float* np = Pnum + ((size_t)bh * 32 + pidx) * 1024;
#pragma unroll
    for (int dblk = 0; dblk < 4; dblk++)
#pragma unroll
      for (int r = 0; r < 4; r++)
        np[(dblk * 16 + g * 4 + r) * 16 + lq] = oacc[dblk][r];
    Pden[((size_t)bh * 32 + pidx) * 16 + lq] = denom;
  }
}

// ---------------------------------------------------------------------------
// Merge global-token partials and overwrite ATT rows < G.
// ---------------------------------------------------------------------------
__global__ __launch_bounds__(512) void gmerge(const float* __restrict__ Pnum,
                                              const float* __restrict__ Pden,
                                              u16* __restrict__ ATT) {
  const int bh = blockIdx.x;
  const int b = bh / HH, h = bh % HH;
  const int t = threadIdx.x;
  const int q = t >> 6, d = t & 63;
  float num = 0.f, den = 0.f;
#pragma unroll 4
  for (int p = 0; p < 32; p++) {
    num += Pnum[((size_t)bh * 32 + p) * 1024 + d * 16 + q];
    den += Pden[((size_t)bh * 32 + p) * 16 + q];
  }
  ATT[((size_t)b * SS + q) * DD + h * 64 + d] = f2b(num / den);
}

// ---------------------------------------------------------------------------
extern "C" void kernel_launch(void* const* d_in, const int* in_sizes, int n_in,
                              void* d_out, int out_size, void* d_ws,
                              size_t ws_size, hipStream_t stream) {
  const float* hs = (const float*)d_in[0];
  const int* amask = (const int*)d_in[1];
  const float* Wq = (const float*)d_in[2];
  const float* bq = (const float*)d_in[3];
  const float* Wk = (const float*)d_in[4];
  const float* bk = (const float*)d_in[5];
  const float* Wv = (const float*)d_in[6];
  const float* bv = (const float*)d_in[7];
  const float* Wqg = (const float*)d_in[8];
  const float* bqg = (const float*)d_in[9];
  const float* Wkg = (const float*)d_in[10];
  const float* bkg = (const float*)d_in[11];
  const float* Wvg = (const float*)d_in[12];
  const float* bvg = (const float*)d_in[13];
  const float* Wo = (const float*)d_in[14];
  const float* bo = (const float*)d_in[15];
  float* out = (float*)d_out;

  char* ws = (char*)d_ws;
  const size_t QSZB = (size_t)BB * HH * SS * HDD * 2;  // 12582912 B
  u16* Qb = (u16*)(ws + 0);
  u16* Kb = (u16*)(ws + QSZB);
  u16* Vb = (u16*)(ws + 2 * QSZB);
  u16* KGb = (u16*)(ws + 3 * QSZB);
  u16* VGb = (u16*)(ws + 4 * QSZB);
  u16* Ab = (u16*)(ws + 5 * QSZB);
  u16* WTb = (u16*)(ws + 6 * QSZB);                     // 7077888 B
  u16* ATTb = (u16*)(ws + 6 * QSZB + 7077888);          // QSZB
  u16* QGb = (u16*)(ws + 7 * QSZB + 7077888);           // 49152 B
  float* Pnum = (float*)(ws + 7 * QSZB + 7077888 + 49152);   // 3145728 B
  float* Pden = (float*)(ws + 7 * QSZB + 7077888 + 49152 + 3145728);  // 49152

  // 1) convert hs -> bf16 A
  hipLaunchKernelGGL(cvt_f32_bf16, dim3(3072), dim3(256), 0, stream, hs, Ab,
                     (int)((size_t)BB * SS * DD / 8));

  // 2) transpose+convert 6 weight matrices -> WT[mat][n][k] bf16
  WtArgs wa;
  wa.W[0] = Wq; wa.W[1] = Wk; wa.W[2] = Wv;
  wa.W[3] = Wkg; wa.W[4] = Wvg; wa.W[5] = Wo;
  hipLaunchKernelGGL(transpose_wt, dim3(12, 12, 6), dim3(256), 0, stream, wa,
                     WTb);

  // 3) fused projections (bf16 MFMA, 3-buffer ring): Q,K,V,KG,VG
  BiasArgs b0;
  b0.bias[0] = bq; b0.bias[1] = bk; b0.bias[2] = bv;
  b0.bias[3] = bkg; b0.bias[4] = bvg;
  hipLaunchKernelGGL((gemm_bf16<0>), dim3(960), dim3(512), 147456, stream,
                     Ab, WTb, b0, Qb, (float*)nullptr);

  // 4) qg projection -> QGb
  hipLaunchKernelGGL(qg_proj, dim3(24), dim3(256), 0, stream, hs, Wqg, bqg,
                     QGb);

  // 5) global-token attention partials (reads KGb/VGb/QGb)
  hipLaunchKernelGGL((attn_mfma<1>), dim3(8, HH, BB), dim3(256), 65536,
                     stream, QGb, KGb, VGb, amask, (u16*)nullptr, Pnum, Pden);

  // 6) banded attention -> ATT (bf16)
  hipLaunchKernelGGL((attn_mfma<0>), dim3(64, HH, BB), dim3(256), 16384,
                     stream, Qb, Kb, Vb, amask, ATTb, (float*)nullptr,
                     (float*)nullptr);

  // 7) merge global-token rows into ATT
  hipLaunchKernelGGL(gmerge, dim3(24), dim3(512), 0, stream, Pnum, Pden, ATTb);

  // 8) output projection (bf16 MFMA, fp32 out)
  BiasArgs b1;
  for (int i = 0; i < 5; i++) b1.bias[i] = bo;
  hipLaunchKernelGGL((gemm_bf16<1>), dim3(192), dim3(512), 147456, stream,
                     ATTb, WTb + (size_t)5 * 768 * 768, b1, (u16*)nullptr,
                     out);
}